// Round 13
// baseline (517.425 us; speedup 1.0000x reference)
//
#include <hip/hip_runtime.h>
#include <cstdint>
#include <cstddef>

#define RANK_K 819            // kth = sorted[819] (820th smallest of 2048)
// conv: x[64,3,32,32] * w[2048,3,6,6] VALID -> [64,2048,27,27]

typedef __attribute__((ext_vector_type(2)))  float f32x2;
typedef __attribute__((ext_vector_type(16))) float f32x16;

// Batched scalar loads: issue 3x s_load_dwordx16 (pipelined in the SMEM unit),
// ONE wait for all, then a sched_barrier so the compiler cannot hoist the
// dependent pk_fma extraction above the wait (guide rule: lgkmcnt + SGB).
__device__ __forceinline__ void sload3x16(const float* r0, const float* r1,
                                          const float* r2,
                                          f32x16& v0, f32x16& v1, f32x16& v2) {
  asm volatile(
      "s_load_dwordx16 %0, %3, 0x0\n\t"
      "s_load_dwordx16 %1, %4, 0x0\n\t"
      "s_load_dwordx16 %2, %5, 0x0\n\t"
      "s_waitcnt lgkmcnt(0)"
      : "=&s"(v0), "=&s"(v1), "=&s"(v2)
      : "s"(r0), "s"(r1), "s"(r2));
  __builtin_amdgcn_sched_barrier(0);
}

// v_pk_fma_f32, src1 = SGPR PAIR (VOP3P sources are 64-bit). op_sel picks the
// half both lanes broadcast from. HW-validated bit-exact (rounds 10/12).
__device__ __forceinline__ f32x2 pk_fma_blo(f32x2 a, f32x2 bs, f32x2 c) {
  f32x2 d;
  asm("v_pk_fma_f32 %0, %1, %2, %3 op_sel_hi:[1,0,1]"
      : "=v"(d) : "v"(a), "s"(bs), "v"(c));
  return d;
}
__device__ __forceinline__ f32x2 pk_fma_bhi(f32x2 a, f32x2 bs, f32x2 c) {
  f32x2 d;
  asm("v_pk_fma_f32 %0, %1, %2, %3 op_sel:[0,1,0] op_sel_hi:[1,1,1]"
      : "=v"(d) : "v"(a), "s"(bs), "v"(c));
  return d;
}

__device__ __forceinline__ int zbin256(float z) {
  // 256 bins over [-8,8), width 1/16. Monotone partition; selection is exact
  // rank within bin, so binning never affects the kth VALUE.
  float t = (z + 8.0f) * 16.0f;
  t = t < 0.0f ? 0.0f : (t > 255.0f ? 255.0f : t);
  return (int)t;
}

// ------- kernel 1: weight pairs wt4[k][cc] = (w[cc][k], w[cc+1024][k]) ------
__global__ __launch_bounds__(256) void net99_wtrans(const float* __restrict__ w,
                                                    f32x2* __restrict__ wt4) {
  int idx = blockIdx.x * 256 + threadIdx.x;
  if (idx < 108 * 1024) {
    int k = idx / 1024, cc = idx % 1024;
    int ic = k % 3, sp = k / 3, ky = sp / 6, kx = sp % 6;
    int wo = ic * 36 + ky * 6 + kx;
    f32x2 t;
    t.x = w[cc * 108 + wo];
    t.y = w[(cc + 1024) * 108 + wo];
    wt4[idx] = t;
  }
}

// ------- kernel 2: f32 conv, col-streaming pk_fma, x via batched s_load -----
// Per output q the chain is still (ky -> kx -> ic) ascending: col m = q+kx
// sweeps ascending => kx ascending; ic innermost. Bit-exact.
__global__ __launch_bounds__(256, 4) void net99_conv(const float* __restrict__ x,
                                                     const f32x2* __restrict__ wt4,
                                                     float* __restrict__ conv, int b0) {
  const int y  = blockIdx.x;       // 0..26
  const int ct = blockIdx.y;       // 0..3 (512-channel tiles)
  const int bl = blockIdx.z;       // local batch
  const int b  = b0 + bl;
  const int tid = threadIdx.x;
  const int cpair = ct * 256 + tid;            // channels cpair, cpair+1024
  const f32x2* wtc = wt4 + cpair;
  f32x2 acc[27];
#pragma unroll
  for (int q = 0; q < 27; ++q) acc[q] = (f32x2)(0.0f);
#pragma unroll 1
  for (int ky = 0; ky < 6; ++ky) {   // runtime loop: code size + SGPR window
    const float* r0 = x + ((b * 3 + 0) * 32 + (y + ky)) * 32;
    const float* r1 = x + ((b * 3 + 1) * 32 + (y + ky)) * 32;
    const float* r2 = x + ((b * 3 + 2) * 32 + (y + ky)) * 32;
    // this ky's 18 weight pairs (coalesced dwordx2, L2-resident)
    f32x2 wv[6][3];
#pragma unroll
    for (int kx = 0; kx < 6; ++kx)
#pragma unroll
      for (int ic = 0; ic < 3; ++ic)
        wv[kx][ic] = wtc[(size_t)((ky * 6 + kx) * 3 + ic) * 1024];
    // half A: cols 0..15 in SGPRs (one batched wait)
    {
      f32x16 a0, a1, a2;
      sload3x16(r0, r1, r2, a0, a1, a2);
#pragma unroll
      for (int m = 0; m < 16; ++m) {
        f32x2 p0, p1, p2;                       // pair holding column m
        p0.x = a0[(m >> 1) * 2]; p0.y = a0[(m >> 1) * 2 + 1];
        p1.x = a1[(m >> 1) * 2]; p1.y = a1[(m >> 1) * 2 + 1];
        p2.x = a2[(m >> 1) * 2]; p2.y = a2[(m >> 1) * 2 + 1];
#pragma unroll
        for (int kx = 0; kx < 6; ++kx) {
          if (kx <= m) {                 // q = m-kx in [0,26] guaranteed
            const int q = m - kx;
            if (m & 1) {
              acc[q] = pk_fma_bhi(wv[kx][0], p0, acc[q]);
              acc[q] = pk_fma_bhi(wv[kx][1], p1, acc[q]);
              acc[q] = pk_fma_bhi(wv[kx][2], p2, acc[q]);
            } else {
              acc[q] = pk_fma_blo(wv[kx][0], p0, acc[q]);
              acc[q] = pk_fma_blo(wv[kx][1], p1, acc[q]);
              acc[q] = pk_fma_blo(wv[kx][2], p2, acc[q]);
            }
          }
        }
      }
    }
    // half B: cols 16..31 in SGPRs (one batched wait)
    {
      f32x16 c0, c1, c2;
      sload3x16(r0 + 16, r1 + 16, r2 + 16, c0, c1, c2);
#pragma unroll
      for (int m = 16; m < 32; ++m) {
        const int mm = m - 16;
        f32x2 p0, p1, p2;
        p0.x = c0[(mm >> 1) * 2]; p0.y = c0[(mm >> 1) * 2 + 1];
        p1.x = c1[(mm >> 1) * 2]; p1.y = c1[(mm >> 1) * 2 + 1];
        p2.x = c2[(mm >> 1) * 2]; p2.y = c2[(mm >> 1) * 2 + 1];
#pragma unroll
        for (int kx = 0; kx < 6; ++kx) {
          const int q = m - kx;
          if (q <= 26) {                 // kx <= 5 <= m always
            if (m & 1) {
              acc[q] = pk_fma_bhi(wv[kx][0], p0, acc[q]);
              acc[q] = pk_fma_bhi(wv[kx][1], p1, acc[q]);
              acc[q] = pk_fma_bhi(wv[kx][2], p2, acc[q]);
            } else {
              acc[q] = pk_fma_blo(wv[kx][0], p0, acc[q]);
              acc[q] = pk_fma_blo(wv[kx][1], p1, acc[q]);
              acc[q] = pk_fma_blo(wv[kx][2], p2, acc[q]);
            }
          }
        }
      }
    }
  }
  float* dstbase = conv + ((size_t)(bl * 27 + y) * 27) * 2048;
#pragma unroll
  for (int q = 0; q < 27; ++q) {
    dstbase[(size_t)q * 2048 + cpair]        = acc[q].x;
    dstbase[(size_t)q * 2048 + cpair + 1024] = acc[q].y;
  }
}

// ------- kernel 3: 4-pixel register-resident rank-819 select + byte mask ----
// UNCHANGED (passing, bit-exact).
__global__ __launch_bounds__(256, 2) void net99_select(const float* __restrict__ conv,
                                                       const float* __restrict__ bias,
                                                       uint8_t* __restrict__ mskb, int b0) {
  const int bl = blockIdx.x / 183;
  const int g  = blockIdx.x % 183;
  const int p0 = 4 * g;
  const int npix = (g < 182) ? 4 : 1;     // 182*4=728, tail block: pixel 728
  const int nst  = 2 * npix;
  const int gb = b0 + bl;
  const int tid  = threadIdx.x;
  const int lane = tid & 63;
  const int wid  = tid >> 6;
  __shared__ uint32_t hist[8][256];       //  8 KB
  __shared__ float    cand[8][512];       // 16 KB
  __shared__ int      cnt[8];
  __shared__ int      sbin[8], sbelow[8];
  __shared__ float    skth[8];

  const float4* __restrict__ s0 =
      (const float4*)(conv + ((size_t)bl * 729 + p0) * 2048) + tid * 2;
  const float4* __restrict__ b4 = (const float4*)bias + tid * 2;
  float4 va[4][2];
#pragma unroll
  for (int k = 0; k < 4; ++k) {
    if (k < npix) { va[k][0] = s0[k * 512]; va[k][1] = s0[k * 512 + 1]; }
    else          { va[k][0] = float4{0,0,0,0}; va[k][1] = float4{0,0,0,0}; }
  }
  float4 ba = b4[0], bb = b4[1];

#pragma unroll
  for (int r = 0; r < 8; ++r) (&hist[0][0])[tid + 256 * r] = 0u;
  if (tid < 8) cnt[tid] = 0;

  float z[8][8];
  {
    float bv[8] = {ba.x, ba.y, ba.z, ba.w, bb.x, bb.y, bb.z, bb.w};
#pragma unroll
    for (int k = 0; k < 4; ++k) {
      float v[8] = {va[k][0].x, va[k][0].y, va[k][0].z, va[k][0].w,
                    va[k][1].x, va[k][1].y, va[k][1].z, va[k][1].w};
#pragma unroll
      for (int j = 0; j < 8; ++j) {
        z[2 * k][j]     = bv[j] - v[j];   // single f32 op, matches reference
        z[2 * k + 1][j] = bv[j] + v[j];
      }
    }
  }
  __syncthreads();                                  // hist zeros visible
#pragma unroll
  for (int s = 0; s < 8; ++s) {
    if (s < nst) {
#pragma unroll
      for (int j = 0; j < 8; ++j) atomicAdd(&hist[s][zbin256(z[s][j])], 1u);
    }
  }
  __syncthreads();
#pragma unroll
  for (int rep = 0; rep < 2; ++rep) {     // wave w scans streams w, w+4
    const int s = wid + 4 * rep;
    if (s < nst) {
      int h[4];
#pragma unroll
      for (int t = 0; t < 4; ++t) h[t] = (int)hist[s][lane * 4 + t];
      int loc = h[0] + h[1] + h[2] + h[3];
      int inc = loc;
#pragma unroll
      for (int off = 1; off < 64; off <<= 1) {
        int u = __shfl_up(inc, off);
        if (lane >= off) inc += u;
      }
      int pre = inc - loc;
      if (pre <= RANK_K && RANK_K < pre + loc) {    // exactly one lane
        int cum = pre;
#pragma unroll
        for (int t = 0; t < 4; ++t) {
          if (RANK_K < cum + h[t]) { sbin[s] = lane * 4 + t; sbelow[s] = cum; break; }
          cum += h[t];
        }
      }
    }
  }
  __syncthreads();
#pragma unroll
  for (int s = 0; s < 8; ++s) {                     // compact from registers
    if (s < nst) {
      const int tb = sbin[s];
#pragma unroll
      for (int j = 0; j < 8; ++j) {
        if (zbin256(z[s][j]) == tb) {
          int u = atomicAdd(&cnt[s], 1);
          if (u < 512) cand[s][u] = z[s][j];
        }
      }
    }
  }
  __syncthreads();
#pragma unroll
  for (int rep = 0; rep < 2; ++rep) {     // exact rank, wave w: streams w, w+4
    const int s = wid + 4 * rep;
    if (s < nst) {
      int cN = cnt[s] < 512 ? cnt[s] : 512;
      int rloc = RANK_K - sbelow[s];
      for (int ci = lane; ci < cN; ci += 64) {
        float v = cand[s][ci]; int rk = 0;
        for (int j = 0; j < cN; ++j) {
          float u = cand[s][j];
          rk += (u < v) || (u == v && j < ci);
        }
        if (rk == rloc) skth[s] = v;                // unique winning VALUE
      }
    }
  }
  __syncthreads();
#pragma unroll
  for (int k = 0; k < 4; ++k) {
    if (k < npix) {
      uint32_t m0 = 0u, m1 = 0u;
      const float k0 = skth[2 * k], k1 = skth[2 * k + 1];
#pragma unroll
      for (int j = 0; j < 8; ++j) {
        m0 |= (uint32_t)(z[2 * k][j] < k0) << j;
        m1 |= (uint32_t)(z[2 * k + 1][j] < k1) << j;
      }
      const size_t pix = (size_t)gb * 729 + p0 + k;
      mskb[pix * 256 + tid]                      = (uint8_t)m0;
      mskb[((size_t)64 * 729 + pix) * 256 + tid] = (uint8_t)m1;
    }
  }
}

// ------- kernel 4: bit-exact avg_pool(5,3,ceil) + adaptive(6), LDS-staged ---
__global__ __launch_bounds__(256) void net99_pool(const uint32_t* __restrict__ msk,
                                                  float* __restrict__ out) {
  __shared__ uint32_t stage[729 * 8];   // 23,328 B: full (s,b,cg) mask slice
  const int blk = blockIdx.x;           // 0..1023 = (sb, cg)
  const int cg  = blk & 7;
  const int sb  = blk >> 3;             // s*64 + b
  const int tid = threadIdx.x;
  const uint32_t* src = msk + (size_t)sb * 729 * 64 + cg * 8;
  for (int i = tid; i < 729 * 8; i += 256) {
    int p = i >> 3, w = i & 7;
    stage[i] = src[(size_t)p * 64 + w];
  }
  __syncthreads();
  const int lw = tid >> 5, sel = tid & 31;
  uint32_t rbm[27];
  for (int y = 0; y < 27; ++y) {
    uint32_t rb = 0;
#pragma unroll
    for (int xx = 0; xx < 27; ++xx)
      rb |= ((stage[(y * 27 + xx) * 8 + lw] >> sel) & 1u) << xx;
    rbm[y] = rb;
  }
  constexpr uint32_t WM[9] = {0x1Fu, 0xF8u, 0x7C0u, 0x3E00u, 0x1F000u,
                              0xF8000u, 0x7C0000u, 0x3E00000u, 0x7000000u};
  constexpr int CC[9]  = {5, 5, 5, 5, 5, 5, 5, 5, 3};
  constexpr int BW0[6] = {0, 1, 3, 4, 6, 7};
  constexpr int BW1[6] = {1, 2, 4, 5, 7, 8};
  const int s = sb >> 6, b = sb & 63, c = cg * 256 + tid;
  float* dst = out + (size_t)s * 4718592 + (size_t)(b * 2048 + c) * 36;
  for (int i = 0; i < 6; ++i) {
    float P[2][9];
#pragma unroll
    for (int t = 0; t < 2; ++t) {
      int r  = t ? BW1[i] : BW0[i];
      int y0 = 3 * r;
      int y1 = (y0 + 5 > 27) ? 27 : y0 + 5;
      int cr = y1 - y0;
      int pp[9];
#pragma unroll
      for (int cx = 0; cx < 9; ++cx) pp[cx] = 0;
      for (int yy = y0; yy < y1; ++yy) {
        uint32_t rb = rbm[yy];
#pragma unroll
        for (int cx = 0; cx < 9; ++cx) pp[cx] += __popc(rb & WM[cx]);
      }
#pragma unroll
      for (int cx = 0; cx < 9; ++cx)
        P[t][cx] = (float)pp[cx] / (float)(cr * CC[cx]);   // IEEE f32 div
    }
    float M[9];
#pragma unroll
    for (int cx = 0; cx < 9; ++cx) M[cx] = (P[0][cx] + P[1][cx]) * 0.5f;
#pragma unroll
    for (int j = 0; j < 6; ++j)
      dst[i * 6 + j] = (M[BW0[j]] + M[BW1[j]]) * 0.5f;
  }
}

extern "C" void kernel_launch(void* const* d_in, const int* in_sizes, int n_in,
                              void* d_out, int out_size, void* d_ws, size_t ws_size,
                              hipStream_t stream) {
  const float* x    = (const float*)d_in[0];
  const float* w    = (const float*)d_in[1];
  const float* bias = (const float*)d_in[2];
  float* out = (float*)d_out;
  uint8_t* ws = (uint8_t*)d_ws;

  const size_t WT_BYTES   = (size_t)108 * 1024 * 8;          //   884,736
  const size_t MASK_OFF   = WT_BYTES;
  const size_t MASK_BYTES = (size_t)2 * 64 * 729 * 64 * 4;   // 23,887,872
  const size_t CONV_OFF   = MASK_OFF + MASK_BYTES;           // 24,772,608
  const size_t PER_B      = (size_t)2048 * 729 * 4;          // 5,971,968 per batch

  f32x2*    wt4  = (f32x2*)ws;
  uint8_t*  mskb = (uint8_t*)(ws + MASK_OFF);
  uint32_t* msk  = (uint32_t*)(ws + MASK_OFF);
  float*    conv = (float*)(ws + CONV_OFF);

  size_t avail = ws_size > CONV_OFF ? ws_size - CONV_OFF : 0;
  int Bc = (int)(avail / PER_B);
  if (Bc < 1) Bc = 1;       // assumes ws_size >= ~31 MB
  if (Bc > 16) Bc = 16;     // 96 MB chunk: conv out + next chunk both fit L3

  hipLaunchKernelGGL(net99_wtrans, dim3((108 * 1024 + 255) / 256), dim3(256), 0, stream, w, wt4);
  for (int b0 = 0; b0 < 64; b0 += Bc) {
    int nb = (64 - b0 < Bc) ? (64 - b0) : Bc;
    hipLaunchKernelGGL(net99_conv, dim3(27, 4, nb), dim3(256), 0, stream, x, wt4, conv, b0);
    hipLaunchKernelGGL(net99_select, dim3(nb * 183), dim3(256), 0, stream, conv, bias, mskb, b0);
  }
  hipLaunchKernelGGL(net99_pool, dim3(1024), dim3(256), 0, stream, msk, out);
}

// Round 14
// 465.121 us; speedup vs baseline: 1.1125x; 1.1125x over previous
//
#include <hip/hip_runtime.h>
#include <cstdint>
#include <cstddef>

#define RANK_K 819            // kth = sorted[819] (820th smallest of 2048)
// conv: x[64,3,32,32] * w[2048,3,6,6] VALID -> [64,2048,27,27]

typedef __attribute__((ext_vector_type(2)))  float f32x2;
typedef __attribute__((ext_vector_type(16))) float f32x16;

// Batched scalar loads: issue 3x s_load_dwordx16 (pipelined in the SMEM unit),
// ONE wait for all, then a sched_barrier so the compiler cannot hoist the
// dependent pk_fma extraction above the wait (guide rule: lgkmcnt + SGB).
__device__ __forceinline__ void sload3x16(const float* r0, const float* r1,
                                          const float* r2,
                                          f32x16& v0, f32x16& v1, f32x16& v2) {
  asm volatile(
      "s_load_dwordx16 %0, %3, 0x0\n\t"
      "s_load_dwordx16 %1, %4, 0x0\n\t"
      "s_load_dwordx16 %2, %5, 0x0\n\t"
      "s_waitcnt lgkmcnt(0)"
      : "=&s"(v0), "=&s"(v1), "=&s"(v2)
      : "s"(r0), "s"(r1), "s"(r2));
  __builtin_amdgcn_sched_barrier(0);
}

// v_pk_fma_f32, src1 = SGPR PAIR (VOP3P sources are 64-bit). op_sel picks the
// half both lanes broadcast from. HW-validated bit-exact (rounds 10/12).
__device__ __forceinline__ f32x2 pk_fma_blo(f32x2 a, f32x2 bs, f32x2 c) {
  f32x2 d;
  asm("v_pk_fma_f32 %0, %1, %2, %3 op_sel_hi:[1,0,1]"
      : "=v"(d) : "v"(a), "s"(bs), "v"(c));
  return d;
}
__device__ __forceinline__ f32x2 pk_fma_bhi(f32x2 a, f32x2 bs, f32x2 c) {
  f32x2 d;
  asm("v_pk_fma_f32 %0, %1, %2, %3 op_sel:[0,1,0] op_sel_hi:[1,1,1]"
      : "=v"(d) : "v"(a), "s"(bs), "v"(c));
  return d;
}

__device__ __forceinline__ int zbin256(float z) {
  // 256 bins over [-8,8), width 1/16. Monotone partition; selection is exact
  // rank within bin, so binning never affects the kth VALUE.
  float t = (z + 8.0f) * 16.0f;
  t = t < 0.0f ? 0.0f : (t > 255.0f ? 255.0f : t);
  return (int)t;
}

// ------- kernel 1: weight pairs wt4[k][cc] = (w[cc][k], w[cc+1024][k]) ------
__global__ __launch_bounds__(256) void net99_wtrans(const float* __restrict__ w,
                                                    f32x2* __restrict__ wt4) {
  int idx = blockIdx.x * 256 + threadIdx.x;
  if (idx < 108 * 1024) {
    int k = idx / 1024, cc = idx % 1024;
    int ic = k % 3, sp = k / 3, ky = sp / 6, kx = sp % 6;
    int wo = ic * 36 + ky * 6 + kx;
    f32x2 t;
    t.x = w[cc * 108 + wo];
    t.y = w[(cc + 1024) * 108 + wo];
    wt4[idx] = t;
  }
}

// ------- kernel 2: f32 conv, col-streaming pk_fma, x via batched s_load -----
// Per output q the chain is still (ky -> kx -> ic) ascending: col m = q+kx
// sweeps ascending => kx ascending; ic innermost. Bit-exact.
__global__ __launch_bounds__(256, 4) void net99_conv(const float* __restrict__ x,
                                                     const f32x2* __restrict__ wt4,
                                                     float* __restrict__ conv, int b0) {
  const int y  = blockIdx.x;       // 0..26
  const int ct = blockIdx.y;       // 0..3 (512-channel tiles)
  const int bl = blockIdx.z;       // local batch
  const int b  = b0 + bl;
  const int tid = threadIdx.x;
  const int cpair = ct * 256 + tid;            // channels cpair, cpair+1024
  const f32x2* wtc = wt4 + cpair;
  f32x2 acc[27];
#pragma unroll
  for (int q = 0; q < 27; ++q) acc[q] = (f32x2)(0.0f);
#pragma unroll 1
  for (int ky = 0; ky < 6; ++ky) {   // runtime loop: code size + SGPR window
    const float* r0 = x + ((b * 3 + 0) * 32 + (y + ky)) * 32;
    const float* r1 = x + ((b * 3 + 1) * 32 + (y + ky)) * 32;
    const float* r2 = x + ((b * 3 + 2) * 32 + (y + ky)) * 32;
    // this ky's 18 weight pairs (coalesced dwordx2, L2-resident)
    f32x2 wv[6][3];
#pragma unroll
    for (int kx = 0; kx < 6; ++kx)
#pragma unroll
      for (int ic = 0; ic < 3; ++ic)
        wv[kx][ic] = wtc[(size_t)((ky * 6 + kx) * 3 + ic) * 1024];
    // half A: cols 0..15 in SGPRs (one batched wait)
    {
      f32x16 a0, a1, a2;
      sload3x16(r0, r1, r2, a0, a1, a2);
#pragma unroll
      for (int m = 0; m < 16; ++m) {
        f32x2 p0, p1, p2;                       // pair holding column m
        p0.x = a0[(m >> 1) * 2]; p0.y = a0[(m >> 1) * 2 + 1];
        p1.x = a1[(m >> 1) * 2]; p1.y = a1[(m >> 1) * 2 + 1];
        p2.x = a2[(m >> 1) * 2]; p2.y = a2[(m >> 1) * 2 + 1];
#pragma unroll
        for (int kx = 0; kx < 6; ++kx) {
          if (kx <= m) {                 // q = m-kx in [0,26] guaranteed
            const int q = m - kx;
            if (m & 1) {
              acc[q] = pk_fma_bhi(wv[kx][0], p0, acc[q]);
              acc[q] = pk_fma_bhi(wv[kx][1], p1, acc[q]);
              acc[q] = pk_fma_bhi(wv[kx][2], p2, acc[q]);
            } else {
              acc[q] = pk_fma_blo(wv[kx][0], p0, acc[q]);
              acc[q] = pk_fma_blo(wv[kx][1], p1, acc[q]);
              acc[q] = pk_fma_blo(wv[kx][2], p2, acc[q]);
            }
          }
        }
      }
    }
    // half B: cols 16..31 in SGPRs (one batched wait)
    {
      f32x16 c0, c1, c2;
      sload3x16(r0 + 16, r1 + 16, r2 + 16, c0, c1, c2);
#pragma unroll
      for (int m = 16; m < 32; ++m) {
        const int mm = m - 16;
        f32x2 p0, p1, p2;
        p0.x = c0[(mm >> 1) * 2]; p0.y = c0[(mm >> 1) * 2 + 1];
        p1.x = c1[(mm >> 1) * 2]; p1.y = c1[(mm >> 1) * 2 + 1];
        p2.x = c2[(mm >> 1) * 2]; p2.y = c2[(mm >> 1) * 2 + 1];
#pragma unroll
        for (int kx = 0; kx < 6; ++kx) {
          const int q = m - kx;
          if (q <= 26) {                 // kx <= 5 <= m always
            if (m & 1) {
              acc[q] = pk_fma_bhi(wv[kx][0], p0, acc[q]);
              acc[q] = pk_fma_bhi(wv[kx][1], p1, acc[q]);
              acc[q] = pk_fma_bhi(wv[kx][2], p2, acc[q]);
            } else {
              acc[q] = pk_fma_blo(wv[kx][0], p0, acc[q]);
              acc[q] = pk_fma_blo(wv[kx][1], p1, acc[q]);
              acc[q] = pk_fma_blo(wv[kx][2], p2, acc[q]);
            }
          }
        }
      }
    }
  }
  float* dstbase = conv + ((size_t)(bl * 27 + y) * 27) * 2048;
#pragma unroll
  for (int q = 0; q < 27; ++q) {
    dstbase[(size_t)q * 2048 + cpair]        = acc[q].x;
    dstbase[(size_t)q * 2048 + cpair + 1024] = acc[q].y;
  }
}

// ------- kernel 3: 4-pixel register-resident rank-819 select + byte mask ----
// cand shrunk to 256/stream (max bin occupancy ~50 of 2048 N-samples in a
// 1/16 bin; 5x margin). LDS 17 KB -> ~9 blocks/CU for latency hiding.
__global__ __launch_bounds__(256, 4) void net99_select(const float* __restrict__ conv,
                                                       const float* __restrict__ bias,
                                                       uint8_t* __restrict__ mskb, int b0) {
  const int bl = blockIdx.x / 183;
  const int g  = blockIdx.x % 183;
  const int p0 = 4 * g;
  const int npix = (g < 182) ? 4 : 1;     // 182*4=728, tail block: pixel 728
  const int nst  = 2 * npix;
  const int gb = b0 + bl;
  const int tid  = threadIdx.x;
  const int lane = tid & 63;
  const int wid  = tid >> 6;
  __shared__ uint32_t hist[8][256];       //  8 KB
  __shared__ float    cand[8][256];       //  8 KB
  __shared__ int      cnt[8];
  __shared__ int      sbin[8], sbelow[8];
  __shared__ float    skth[8];

  const float4* __restrict__ s0 =
      (const float4*)(conv + ((size_t)bl * 729 + p0) * 2048) + tid * 2;
  const float4* __restrict__ b4 = (const float4*)bias + tid * 2;
  float4 va[4][2];
#pragma unroll
  for (int k = 0; k < 4; ++k) {
    if (k < npix) { va[k][0] = s0[k * 512]; va[k][1] = s0[k * 512 + 1]; }
    else          { va[k][0] = float4{0,0,0,0}; va[k][1] = float4{0,0,0,0}; }
  }
  float4 ba = b4[0], bb = b4[1];

#pragma unroll
  for (int r = 0; r < 8; ++r) (&hist[0][0])[tid + 256 * r] = 0u;
  if (tid < 8) cnt[tid] = 0;

  float z[8][8];
  {
    float bv[8] = {ba.x, ba.y, ba.z, ba.w, bb.x, bb.y, bb.z, bb.w};
#pragma unroll
    for (int k = 0; k < 4; ++k) {
      float v[8] = {va[k][0].x, va[k][0].y, va[k][0].z, va[k][0].w,
                    va[k][1].x, va[k][1].y, va[k][1].z, va[k][1].w};
#pragma unroll
      for (int j = 0; j < 8; ++j) {
        z[2 * k][j]     = bv[j] - v[j];   // single f32 op, matches reference
        z[2 * k + 1][j] = bv[j] + v[j];
      }
    }
  }
  __syncthreads();                                  // hist zeros visible
#pragma unroll
  for (int s = 0; s < 8; ++s) {
    if (s < nst) {
#pragma unroll
      for (int j = 0; j < 8; ++j) atomicAdd(&hist[s][zbin256(z[s][j])], 1u);
    }
  }
  __syncthreads();
#pragma unroll
  for (int rep = 0; rep < 2; ++rep) {     // wave w scans streams w, w+4
    const int s = wid + 4 * rep;
    if (s < nst) {
      int h[4];
#pragma unroll
      for (int t = 0; t < 4; ++t) h[t] = (int)hist[s][lane * 4 + t];
      int loc = h[0] + h[1] + h[2] + h[3];
      int inc = loc;
#pragma unroll
      for (int off = 1; off < 64; off <<= 1) {
        int u = __shfl_up(inc, off);
        if (lane >= off) inc += u;
      }
      int pre = inc - loc;
      if (pre <= RANK_K && RANK_K < pre + loc) {    // exactly one lane
        int cum = pre;
#pragma unroll
        for (int t = 0; t < 4; ++t) {
          if (RANK_K < cum + h[t]) { sbin[s] = lane * 4 + t; sbelow[s] = cum; break; }
          cum += h[t];
        }
      }
    }
  }
  __syncthreads();
#pragma unroll
  for (int s = 0; s < 8; ++s) {                     // compact from registers
    if (s < nst) {
      const int tb = sbin[s];
#pragma unroll
      for (int j = 0; j < 8; ++j) {
        if (zbin256(z[s][j]) == tb) {
          int u = atomicAdd(&cnt[s], 1);
          if (u < 256) cand[s][u] = z[s][j];
        }
      }
    }
  }
  __syncthreads();
#pragma unroll
  for (int rep = 0; rep < 2; ++rep) {     // exact rank, wave w: streams w, w+4
    const int s = wid + 4 * rep;
    if (s < nst) {
      int cN = cnt[s] < 256 ? cnt[s] : 256;
      int rloc = RANK_K - sbelow[s];
      for (int ci = lane; ci < cN; ci += 64) {
        float v = cand[s][ci]; int rk = 0;
        for (int j = 0; j < cN; ++j) {
          float u = cand[s][j];
          rk += (u < v) || (u == v && j < ci);
        }
        if (rk == rloc) skth[s] = v;                // unique winning VALUE
      }
    }
  }
  __syncthreads();
#pragma unroll
  for (int k = 0; k < 4; ++k) {
    if (k < npix) {
      uint32_t m0 = 0u, m1 = 0u;
      const float k0 = skth[2 * k], k1 = skth[2 * k + 1];
#pragma unroll
      for (int j = 0; j < 8; ++j) {
        m0 |= (uint32_t)(z[2 * k][j] < k0) << j;
        m1 |= (uint32_t)(z[2 * k + 1][j] < k1) << j;
      }
      const size_t pix = (size_t)gb * 729 + p0 + k;
      mskb[pix * 256 + tid]                      = (uint8_t)m0;
      mskb[((size_t)64 * 729 + pix) * 256 + tid] = (uint8_t)m1;
    }
  }
}

// ------- kernel 4: bit-exact avg_pool(5,3,ceil) + adaptive(6), LDS-staged ---
__global__ __launch_bounds__(256) void net99_pool(const uint32_t* __restrict__ msk,
                                                  float* __restrict__ out) {
  __shared__ uint32_t stage[729 * 8];   // 23,328 B: full (s,b,cg) mask slice
  const int blk = blockIdx.x;           // 0..1023 = (sb, cg)
  const int cg  = blk & 7;
  const int sb  = blk >> 3;             // s*64 + b
  const int tid = threadIdx.x;
  const uint32_t* src = msk + (size_t)sb * 729 * 64 + cg * 8;
  for (int i = tid; i < 729 * 8; i += 256) {
    int p = i >> 3, w = i & 7;
    stage[i] = src[(size_t)p * 64 + w];
  }
  __syncthreads();
  const int lw = tid >> 5, sel = tid & 31;
  uint32_t rbm[27];
  for (int y = 0; y < 27; ++y) {
    uint32_t rb = 0;
#pragma unroll
    for (int xx = 0; xx < 27; ++xx)
      rb |= ((stage[(y * 27 + xx) * 8 + lw] >> sel) & 1u) << xx;
    rbm[y] = rb;
  }
  constexpr uint32_t WM[9] = {0x1Fu, 0xF8u, 0x7C0u, 0x3E00u, 0x1F000u,
                              0xF8000u, 0x7C0000u, 0x3E00000u, 0x7000000u};
  constexpr int CC[9]  = {5, 5, 5, 5, 5, 5, 5, 5, 3};
  constexpr int BW0[6] = {0, 1, 3, 4, 6, 7};
  constexpr int BW1[6] = {1, 2, 4, 5, 7, 8};
  const int s = sb >> 6, b = sb & 63, c = cg * 256 + tid;
  float* dst = out + (size_t)s * 4718592 + (size_t)(b * 2048 + c) * 36;
  for (int i = 0; i < 6; ++i) {
    float P[2][9];
#pragma unroll
    for (int t = 0; t < 2; ++t) {
      int r  = t ? BW1[i] : BW0[i];
      int y0 = 3 * r;
      int y1 = (y0 + 5 > 27) ? 27 : y0 + 5;
      int cr = y1 - y0;
      int pp[9];
#pragma unroll
      for (int cx = 0; cx < 9; ++cx) pp[cx] = 0;
      for (int yy = y0; yy < y1; ++yy) {
        uint32_t rb = rbm[yy];
#pragma unroll
        for (int cx = 0; cx < 9; ++cx) pp[cx] += __popc(rb & WM[cx]);
      }
#pragma unroll
      for (int cx = 0; cx < 9; ++cx)
        P[t][cx] = (float)pp[cx] / (float)(cr * CC[cx]);   // IEEE f32 div
    }
    float M[9];
#pragma unroll
    for (int cx = 0; cx < 9; ++cx) M[cx] = (P[0][cx] + P[1][cx]) * 0.5f;
#pragma unroll
    for (int j = 0; j < 6; ++j)
      dst[i * 6 + j] = (M[BW0[j]] + M[BW1[j]]) * 0.5f;
  }
}

extern "C" void kernel_launch(void* const* d_in, const int* in_sizes, int n_in,
                              void* d_out, int out_size, void* d_ws, size_t ws_size,
                              hipStream_t stream) {
  const float* x    = (const float*)d_in[0];
  const float* w    = (const float*)d_in[1];
  const float* bias = (const float*)d_in[2];
  float* out = (float*)d_out;
  uint8_t* ws = (uint8_t*)d_ws;

  const size_t WT_BYTES   = (size_t)108 * 1024 * 8;          //   884,736
  const size_t MASK_OFF   = WT_BYTES;
  const size_t MASK_BYTES = (size_t)2 * 64 * 729 * 64 * 4;   // 23,887,872
  const size_t CONV_OFF   = MASK_OFF + MASK_BYTES;           // 24,772,608
  const size_t PER_B      = (size_t)2048 * 729 * 4;          // 5,971,968 per batch

  f32x2*    wt4  = (f32x2*)ws;
  uint8_t*  mskb = (uint8_t*)(ws + MASK_OFF);
  uint32_t* msk  = (uint32_t*)(ws + MASK_OFF);
  float*    conv = (float*)(ws + CONV_OFF);

  size_t avail = ws_size > CONV_OFF ? ws_size - CONV_OFF : 0;
  int Bc = (int)(avail / PER_B);
  if (Bc < 1) Bc = 1;       // assumes ws_size >= ~31 MB
  if (Bc > 64) Bc = 64;     // revert to max chunk (round-13: small chunks hurt)

  hipLaunchKernelGGL(net99_wtrans, dim3((108 * 1024 + 255) / 256), dim3(256), 0, stream, w, wt4);
  for (int b0 = 0; b0 < 64; b0 += Bc) {
    int nb = (64 - b0 < Bc) ? (64 - b0) : Bc;
    hipLaunchKernelGGL(net99_conv, dim3(27, 4, nb), dim3(256), 0, stream, x, wt4, conv, b0);
    hipLaunchKernelGGL(net99_select, dim3(nb * 183), dim3(256), 0, stream, conv, bias, mskb, b0);
  }
  hipLaunchKernelGGL(net99_pool, dim3(1024), dim3(256), 0, stream, msk, out);
}

// Round 15
// 460.065 us; speedup vs baseline: 1.1247x; 1.0110x over previous
//
#include <hip/hip_runtime.h>
#include <cstdint>
#include <cstddef>

#define RANK_K 819            // kth = sorted[819] (820th smallest of 2048)
// conv: x[64,3,32,32] * w[2048,3,6,6] VALID -> [64,2048,27,27]

typedef __attribute__((ext_vector_type(2)))  float f32x2;
typedef __attribute__((ext_vector_type(4)))  float f32x4s;
typedef __attribute__((ext_vector_type(16))) float f32x16;

// v_pk_fma_f32, src1 = SGPR PAIR (VOP3P sources are 64-bit). op_sel picks the
// half both lanes broadcast from. HW-validated bit-exact (rounds 10/12).
__device__ __forceinline__ f32x2 pk_fma_blo(f32x2 a, f32x2 bs, f32x2 c) {
  f32x2 d;
  asm("v_pk_fma_f32 %0, %1, %2, %3 op_sel_hi:[1,0,1]"
      : "=v"(d) : "v"(a), "s"(bs), "v"(c));
  return d;
}
__device__ __forceinline__ f32x2 pk_fma_bhi(f32x2 a, f32x2 bs, f32x2 c) {
  f32x2 d;
  asm("v_pk_fma_f32 %0, %1, %2, %3 op_sel:[0,1,0] op_sel_hi:[1,1,1]"
      : "=v"(d) : "v"(a), "s"(bs), "v"(c));
  return d;
}

__device__ __forceinline__ int zbin256(float z) {
  // 256 bins over [-8,8), width 1/16. Monotone partition; selection is exact
  // rank within bin, so binning never affects the kth VALUE.
  float t = (z + 8.0f) * 16.0f;
  t = t < 0.0f ? 0.0f : (t > 255.0f ? 255.0f : t);
  return (int)t;
}

// ------- kernel 1: weight pairs wt4[k][cc] = (w[cc][k], w[cc+1024][k]) ------
__global__ __launch_bounds__(256) void net99_wtrans(const float* __restrict__ w,
                                                    f32x2* __restrict__ wt4) {
  int idx = blockIdx.x * 256 + threadIdx.x;
  if (idx < 108 * 1024) {
    int k = idx / 1024, cc = idx % 1024;
    int ic = k % 3, sp = k / 3, ky = sp / 6, kx = sp % 6;
    int wo = ic * 36 + ky * 6 + kx;
    f32x2 t;
    t.x = w[cc * 108 + wo];
    t.y = w[(cc + 1024) * 108 + wo];
    wt4[idx] = t;
  }
}

// ------- kernel 2: f32 conv, q-split col-streaming pk_fma, x via s_load -----
// blockIdx.y = ct(0..3) | qh<<2. qh half computes acc for q = q0..q0+13
// (q0 = 13*qh); qh=0 writes q 0..13, qh=1 writes q 14..26 (q=13 overlap is
// computed bit-identically in both). One batched SMEM wait per ky. Per-output
// chain (ky -> kx ascending -> ic) unchanged -> bit-exact.
__global__ __launch_bounds__(256, 4) void net99_conv(const float* __restrict__ x,
                                                     const f32x2* __restrict__ wt4,
                                                     float* __restrict__ conv, int b0) {
  const int y   = blockIdx.x;       // 0..26
  const int ctq = blockIdx.y;       // 0..7
  const int ct  = ctq & 3;
  const int qh  = ctq >> 2;         // 0: q 0..13 (cols 0..19), 1: q 13..26 (cols 13..31)
  const int bl  = blockIdx.z;
  const int b   = b0 + bl;
  const int tid = threadIdx.x;
  const int q0  = 13 * qh;
  const int cpair = ct * 256 + tid;            // channels cpair, cpair+1024
  const f32x2* wtc = wt4 + cpair;
  f32x2 acc[14];
#pragma unroll
  for (int q = 0; q < 14; ++q) acc[q] = (f32x2)(0.0f);
#pragma unroll 1
  for (int ky = 0; ky < 6; ++ky) {
    const float* r0 = x + ((b * 3 + 0) * 32 + (y + ky)) * 32 + q0;
    const float* r1 = x + ((b * 3 + 1) * 32 + (y + ky)) * 32 + q0;
    const float* r2 = x + ((b * 3 + 2) * 32 + (y + ky)) * 32 + q0;
    // this ky's 18 weight pairs (coalesced dwordx2, L2-resident)
    f32x2 wv[6][3];
#pragma unroll
    for (int kx = 0; kx < 6; ++kx)
#pragma unroll
      for (int ic = 0; ic < 3; ++ic)
        wv[kx][ic] = wtc[(size_t)((ky * 6 + kx) * 3 + ic) * 1024];
    // cols q0..q0+19 into SGPRs: 3x dwordx16 + 3x dwordx4, ONE wait.
    // (r=19 only feeds guarded-out terms; its garbage slot is never used.)
    f32x16 a0, a1, a2; f32x4s e0, e1, e2;
    asm volatile(
        "s_load_dwordx16 %0, %6, 0x0\n\t"
        "s_load_dwordx16 %1, %7, 0x0\n\t"
        "s_load_dwordx16 %2, %8, 0x0\n\t"
        "s_load_dwordx4  %3, %6, 0x40\n\t"
        "s_load_dwordx4  %4, %7, 0x40\n\t"
        "s_load_dwordx4  %5, %8, 0x40\n\t"
        "s_waitcnt lgkmcnt(0)"
        : "=&s"(a0), "=&s"(a1), "=&s"(a2), "=&s"(e0), "=&s"(e1), "=&s"(e2)
        : "s"(r0), "s"(r1), "s"(r2));
    __builtin_amdgcn_sched_barrier(0);
#pragma unroll
    for (int r = 0; r < 19; ++r) {            // col m = q0 + r
      f32x2 p0, p1, p2;                       // SGPR pair holding col m
      if (r < 16) {
        p0.x = a0[(r >> 1) * 2]; p0.y = a0[(r >> 1) * 2 + 1];
        p1.x = a1[(r >> 1) * 2]; p1.y = a1[(r >> 1) * 2 + 1];
        p2.x = a2[(r >> 1) * 2]; p2.y = a2[(r >> 1) * 2 + 1];
      } else {
        const int rr = r - 16;
        p0.x = e0[(rr >> 1) * 2]; p0.y = e0[(rr >> 1) * 2 + 1];
        p1.x = e1[(rr >> 1) * 2]; p1.y = e1[(rr >> 1) * 2 + 1];
        p2.x = e2[(rr >> 1) * 2]; p2.y = e2[(rr >> 1) * 2 + 1];
      }
#pragma unroll
      for (int kx = 0; kx < 6; ++kx) {
        const int qi = r - kx;                // static guard: 0 <= qi < 14
        if (qi >= 0 && qi < 14) {
          if (r & 1) {
            acc[qi] = pk_fma_bhi(wv[kx][0], p0, acc[qi]);
            acc[qi] = pk_fma_bhi(wv[kx][1], p1, acc[qi]);
            acc[qi] = pk_fma_bhi(wv[kx][2], p2, acc[qi]);
          } else {
            acc[qi] = pk_fma_blo(wv[kx][0], p0, acc[qi]);
            acc[qi] = pk_fma_blo(wv[kx][1], p1, acc[qi]);
            acc[qi] = pk_fma_blo(wv[kx][2], p2, acc[qi]);
          }
        }
      }
    }
  }
  float* dstbase = conv + ((size_t)(bl * 27 + y) * 27) * 2048;
  const int qstart = qh;                      // qh=0: write q 0..13; qh=1: 14..26
#pragma unroll
  for (int qi = 0; qi < 14; ++qi) {
    if (qi >= qstart) {
      const int q = q0 + qi;
      dstbase[(size_t)q * 2048 + cpair]        = acc[qi].x;
      dstbase[(size_t)q * 2048 + cpair + 1024] = acc[qi].y;
    }
  }
}

// ------- kernel 3: 2-pixel register-resident rank-819 select + byte mask ----
// Round-7 version restored verbatim (best measured: 2.53 us/batch).
__global__ __launch_bounds__(256) void net99_select(const float* __restrict__ conv,
                                                    const float* __restrict__ bias,
                                                    uint8_t* __restrict__ mskb, int b0) {
  const int bl = blockIdx.x / 365;
  const int g  = blockIdx.x % 365;
  const int p0 = 2 * g;
  const bool has1 = (p0 + 1) < 729;
  const int gb = b0 + bl;
  const int tid  = threadIdx.x;
  const int lane = tid & 63;
  const int wid  = tid >> 6;
  const int nst  = has1 ? 4 : 2;
  __shared__ uint32_t hist[4][256];
  __shared__ float    cand[4][512];
  __shared__ int      cnt[4];
  __shared__ int      sbin[4], sbelow[4];
  __shared__ float    skth[4];

  const float4* __restrict__ s0 =
      (const float4*)(conv + ((size_t)bl * 729 + p0) * 2048) + tid * 2;
  const float4* __restrict__ b4 = (const float4*)bias + tid * 2;
  float4 va0 = s0[0], vb0 = s0[1];
  float4 va1 = {}, vb1 = {};
  if (has1) { va1 = s0[512]; vb1 = s0[513]; }
  float4 ba = b4[0], bb = b4[1];

  (&hist[0][0])[tid]       = 0u;
  (&hist[0][0])[tid + 256] = 0u;
  (&hist[0][0])[tid + 512] = 0u;
  (&hist[0][0])[tid + 768] = 0u;
  if (tid < 4) cnt[tid] = 0;

  float z[4][8];
  {
    float bv[8] = {ba.x, ba.y, ba.z, ba.w, bb.x, bb.y, bb.z, bb.w};
    float v0[8] = {va0.x, va0.y, va0.z, va0.w, vb0.x, vb0.y, vb0.z, vb0.w};
    float v1[8] = {va1.x, va1.y, va1.z, va1.w, vb1.x, vb1.y, vb1.z, vb1.w};
#pragma unroll
    for (int j = 0; j < 8; ++j) {
      z[0][j] = bv[j] - v0[j];   // single f32 op, matches reference
      z[1][j] = bv[j] + v0[j];
      z[2][j] = bv[j] - v1[j];
      z[3][j] = bv[j] + v1[j];
    }
  }
  __syncthreads();                                  // hist zeros visible
#pragma unroll
  for (int j = 0; j < 8; ++j) {
    atomicAdd(&hist[0][zbin256(z[0][j])], 1u);
    atomicAdd(&hist[1][zbin256(z[1][j])], 1u);
  }
  if (has1) {
#pragma unroll
    for (int j = 0; j < 8; ++j) {
      atomicAdd(&hist[2][zbin256(z[2][j])], 1u);
      atomicAdd(&hist[3][zbin256(z[3][j])], 1u);
    }
  }
  __syncthreads();
  if (wid < nst) {                      // wave w scans stream w (no barriers)
    const int s = wid;
    int h[4];
#pragma unroll
    for (int t = 0; t < 4; ++t) h[t] = (int)hist[s][lane * 4 + t];
    int loc = h[0] + h[1] + h[2] + h[3];
    int inc = loc;
#pragma unroll
    for (int off = 1; off < 64; off <<= 1) {
      int u = __shfl_up(inc, off);
      if (lane >= off) inc += u;
    }
    int pre = inc - loc;
    if (pre <= RANK_K && RANK_K < pre + loc) {      // exactly one lane
      int cum = pre;
#pragma unroll
      for (int t = 0; t < 4; ++t) {
        if (RANK_K < cum + h[t]) { sbin[s] = lane * 4 + t; sbelow[s] = cum; break; }
        cum += h[t];
      }
    }
  }
  __syncthreads();
#pragma unroll
  for (int s = 0; s < 4; ++s) {                     // compact from registers
    if (s >= 2 && !has1) break;
    const int tb = sbin[s];
#pragma unroll
    for (int j = 0; j < 8; ++j) {
      if (zbin256(z[s][j]) == tb) {
        int u = atomicAdd(&cnt[s], 1);
        if (u < 512) cand[s][u] = z[s][j];
      }
    }
  }
  __syncthreads();
  if (wid < nst) {                      // exact rank, one wave per stream
    const int s = wid;
    int cN = cnt[s] < 512 ? cnt[s] : 512;
    int rloc = RANK_K - sbelow[s];
    for (int ci = lane; ci < cN; ci += 64) {
      float v = cand[s][ci]; int rk = 0;
      for (int j = 0; j < cN; ++j) {
        float u = cand[s][j];
        rk += (u < v) || (u == v && j < ci);
      }
      if (rk == rloc) skth[s] = v;                  // unique winning VALUE
    }
  }
  __syncthreads();
  const size_t pix0 = (size_t)gb * 729 + p0;
  {
    uint32_t m0 = 0u, m1 = 0u;
    const float k0 = skth[0], k1 = skth[1];
#pragma unroll
    for (int j = 0; j < 8; ++j) {
      m0 |= (uint32_t)(z[0][j] < k0) << j;
      m1 |= (uint32_t)(z[1][j] < k1) << j;
    }
    mskb[pix0 * 256 + tid]                      = (uint8_t)m0;
    mskb[((size_t)64 * 729 + pix0) * 256 + tid] = (uint8_t)m1;
  }
  if (has1) {
    uint32_t m2 = 0u, m3 = 0u;
    const float k2 = skth[2], k3 = skth[3];
#pragma unroll
    for (int j = 0; j < 8; ++j) {
      m2 |= (uint32_t)(z[2][j] < k2) << j;
      m3 |= (uint32_t)(z[3][j] < k3) << j;
    }
    mskb[(pix0 + 1) * 256 + tid]                      = (uint8_t)m2;
    mskb[((size_t)64 * 729 + pix0 + 1) * 256 + tid]   = (uint8_t)m3;
  }
}

// ------- kernel 4: bit-exact avg_pool(5,3,ceil) + adaptive(6), LDS-staged ---
__global__ __launch_bounds__(256) void net99_pool(const uint32_t* __restrict__ msk,
                                                  float* __restrict__ out) {
  __shared__ uint32_t stage[729 * 8];   // 23,328 B: full (s,b,cg) mask slice
  const int blk = blockIdx.x;           // 0..1023 = (sb, cg)
  const int cg  = blk & 7;
  const int sb  = blk >> 3;             // s*64 + b
  const int tid = threadIdx.x;
  const uint32_t* src = msk + (size_t)sb * 729 * 64 + cg * 8;
  for (int i = tid; i < 729 * 8; i += 256) {
    int p = i >> 3, w = i & 7;
    stage[i] = src[(size_t)p * 64 + w];
  }
  __syncthreads();
  const int lw = tid >> 5, sel = tid & 31;
  uint32_t rbm[27];
  for (int y = 0; y < 27; ++y) {
    uint32_t rb = 0;
#pragma unroll
    for (int xx = 0; xx < 27; ++xx)
      rb |= ((stage[(y * 27 + xx) * 8 + lw] >> sel) & 1u) << xx;
    rbm[y] = rb;
  }
  constexpr uint32_t WM[9] = {0x1Fu, 0xF8u, 0x7C0u, 0x3E00u, 0x1F000u,
                              0xF8000u, 0x7C0000u, 0x3E00000u, 0x7000000u};
  constexpr int CC[9]  = {5, 5, 5, 5, 5, 5, 5, 5, 3};
  constexpr int BW0[6] = {0, 1, 3, 4, 6, 7};
  constexpr int BW1[6] = {1, 2, 4, 5, 7, 8};
  const int s = sb >> 6, b = sb & 63, c = cg * 256 + tid;
  float* dst = out + (size_t)s * 4718592 + (size_t)(b * 2048 + c) * 36;
  for (int i = 0; i < 6; ++i) {
    float P[2][9];
#pragma unroll
    for (int t = 0; t < 2; ++t) {
      int r  = t ? BW1[i] : BW0[i];
      int y0 = 3 * r;
      int y1 = (y0 + 5 > 27) ? 27 : y0 + 5;
      int cr = y1 - y0;
      int pp[9];
#pragma unroll
      for (int cx = 0; cx < 9; ++cx) pp[cx] = 0;
      for (int yy = y0; yy < y1; ++yy) {
        uint32_t rb = rbm[yy];
#pragma unroll
        for (int cx = 0; cx < 9; ++cx) pp[cx] += __popc(rb & WM[cx]);
      }
#pragma unroll
      for (int cx = 0; cx < 9; ++cx)
        P[t][cx] = (float)pp[cx] / (float)(cr * CC[cx]);   // IEEE f32 div
    }
    float M[9];
#pragma unroll
    for (int cx = 0; cx < 9; ++cx) M[cx] = (P[0][cx] + P[1][cx]) * 0.5f;
#pragma unroll
    for (int j = 0; j < 6; ++j)
      dst[i * 6 + j] = (M[BW0[j]] + M[BW1[j]]) * 0.5f;
  }
}

extern "C" void kernel_launch(void* const* d_in, const int* in_sizes, int n_in,
                              void* d_out, int out_size, void* d_ws, size_t ws_size,
                              hipStream_t stream) {
  const float* x    = (const float*)d_in[0];
  const float* w    = (const float*)d_in[1];
  const float* bias = (const float*)d_in[2];
  float* out = (float*)d_out;
  uint8_t* ws = (uint8_t*)d_ws;

  const size_t WT_BYTES   = (size_t)108 * 1024 * 8;          //   884,736
  const size_t MASK_OFF   = WT_BYTES;
  const size_t MASK_BYTES = (size_t)2 * 64 * 729 * 64 * 4;   // 23,887,872
  const size_t CONV_OFF   = MASK_OFF + MASK_BYTES;           // 24,772,608
  const size_t PER_B      = (size_t)2048 * 729 * 4;          // 5,971,968 per batch

  f32x2*    wt4  = (f32x2*)ws;
  uint8_t*  mskb = (uint8_t*)(ws + MASK_OFF);
  uint32_t* msk  = (uint32_t*)(ws + MASK_OFF);
  float*    conv = (float*)(ws + CONV_OFF);

  size_t avail = ws_size > CONV_OFF ? ws_size - CONV_OFF : 0;
  int Bc = (int)(avail / PER_B);
  if (Bc < 1) Bc = 1;       // assumes ws_size >= ~31 MB
  if (Bc > 64) Bc = 64;

  hipLaunchKernelGGL(net99_wtrans, dim3((108 * 1024 + 255) / 256), dim3(256), 0, stream, w, wt4);
  for (int b0 = 0; b0 < 64; b0 += Bc) {
    int nb = (64 - b0 < Bc) ? (64 - b0) : Bc;
    hipLaunchKernelGGL(net99_conv, dim3(27, 8, nb), dim3(256), 0, stream, x, wt4, conv, b0);
    hipLaunchKernelGGL(net99_select, dim3(nb * 365), dim3(256), 0, stream, conv, bias, mskb, b0);
  }
  hipLaunchKernelGGL(net99_pool, dim3(1024), dim3(256), 0, stream, msk, out);
}

// Round 16
// 426.831 us; speedup vs baseline: 1.2122x; 1.0779x over previous
//
#include <hip/hip_runtime.h>
#include <cstdint>
#include <cstddef>

#define RANK_K 819            // kth = sorted[819] (820th smallest of 2048)
// conv: x[64,3,32,32] * w[2048,3,6,6] VALID -> [64,2048,27,27]

typedef __attribute__((ext_vector_type(2)))  float f32x2;
typedef __attribute__((ext_vector_type(16))) float f32x16;

// v_pk_fma_f32, src1 = SGPR PAIR (VOP3P sources are 64-bit). op_sel picks the
// half both lanes broadcast from. HW-validated bit-exact (rounds 10/12).
__device__ __forceinline__ f32x2 pk_fma_blo(f32x2 a, f32x2 bs, f32x2 c) {
  f32x2 d;
  asm("v_pk_fma_f32 %0, %1, %2, %3 op_sel_hi:[1,0,1]"
      : "=v"(d) : "v"(a), "s"(bs), "v"(c));
  return d;
}
__device__ __forceinline__ f32x2 pk_fma_bhi(f32x2 a, f32x2 bs, f32x2 c) {
  f32x2 d;
  asm("v_pk_fma_f32 %0, %1, %2, %3 op_sel:[0,1,0] op_sel_hi:[1,1,1]"
      : "=v"(d) : "v"(a), "s"(bs), "v"(c));
  return d;
}

__device__ __forceinline__ int zbin256(float z) {
  // 256 bins over [-8,8), width 1/16. Monotone partition; selection is exact
  // rank within bin, so binning never affects the kth VALUE.
  float t = (z + 8.0f) * 16.0f;
  t = t < 0.0f ? 0.0f : (t > 255.0f ? 255.0f : t);
  return (int)t;
}

// ------- kernel 1: weight pairs wt4[k][cc] = (w[cc][k], w[cc+1024][k]) ------
__global__ __launch_bounds__(256) void net99_wtrans(const float* __restrict__ w,
                                                    f32x2* __restrict__ wt4) {
  int idx = blockIdx.x * 256 + threadIdx.x;
  if (idx < 108 * 1024) {
    int k = idx / 1024, cc = idx % 1024;
    int ic = k % 3, sp = k / 3, ky = sp / 6, kx = sp % 6;
    int wo = ic * 36 + ky * 6 + kx;
    f32x2 t;
    t.x = w[cc * 108 + wo];
    t.y = w[(cc + 1024) * 108 + wo];
    wt4[idx] = t;
  }
}

// ------- kernel 2: f32 conv, col-streaming pk_fma, dep-chain-spread ---------
// Round-14 structure (27 outputs, 2 batched SMEM waits/ky) with the inner
// nesting swapped to ic-outer/kx-inner: consecutive pk_fma target 6 DIFFERENT
// accumulators (dep spacing 6 insts = 24 cyc > pk latency). Per-output q the
// term order is still (ky asc, kx asc, ic asc) -> bit-exact.
__global__ __launch_bounds__(256, 4) void net99_conv(const float* __restrict__ x,
                                                     const f32x2* __restrict__ wt4,
                                                     float* __restrict__ conv, int b0) {
  const int y  = blockIdx.x;       // 0..26
  const int ct = blockIdx.y;       // 0..3 (512-channel tiles)
  const int bl = blockIdx.z;       // local batch
  const int b  = b0 + bl;
  const int tid = threadIdx.x;
  const int cpair = ct * 256 + tid;            // channels cpair, cpair+1024
  const f32x2* wtc = wt4 + cpair;
  f32x2 acc[27];
#pragma unroll
  for (int q = 0; q < 27; ++q) acc[q] = (f32x2)(0.0f);
#pragma unroll 1
  for (int ky = 0; ky < 6; ++ky) {   // runtime loop: code size + SGPR window
    const float* r0 = x + ((b * 3 + 0) * 32 + (y + ky)) * 32;
    const float* r1 = x + ((b * 3 + 1) * 32 + (y + ky)) * 32;
    const float* r2 = x + ((b * 3 + 2) * 32 + (y + ky)) * 32;
    // this ky's 18 weight pairs (coalesced dwordx2, L2-resident)
    f32x2 wv[6][3];
#pragma unroll
    for (int kx = 0; kx < 6; ++kx)
#pragma unroll
      for (int ic = 0; ic < 3; ++ic)
        wv[kx][ic] = wtc[(size_t)((ky * 6 + kx) * 3 + ic) * 1024];
    // half A: cols 0..15 in SGPRs (one batched wait)
    {
      f32x16 a0, a1, a2;
      asm volatile(
          "s_load_dwordx16 %0, %3, 0x0\n\t"
          "s_load_dwordx16 %1, %4, 0x0\n\t"
          "s_load_dwordx16 %2, %5, 0x0\n\t"
          "s_waitcnt lgkmcnt(0)"
          : "=&s"(a0), "=&s"(a1), "=&s"(a2)
          : "s"(r0), "s"(r1), "s"(r2));
      __builtin_amdgcn_sched_barrier(0);
#pragma unroll
      for (int m = 0; m < 16; ++m) {
        f32x2 p[3];                             // SGPR pairs holding col m
        p[0].x = a0[(m >> 1) * 2]; p[0].y = a0[(m >> 1) * 2 + 1];
        p[1].x = a1[(m >> 1) * 2]; p[1].y = a1[(m >> 1) * 2 + 1];
        p[2].x = a2[(m >> 1) * 2]; p[2].y = a2[(m >> 1) * 2 + 1];
#pragma unroll
        for (int ic = 0; ic < 3; ++ic) {        // ic OUTER: spreads dep chains
#pragma unroll
          for (int kx = 0; kx < 6; ++kx) {
            if (kx <= m) {               // q = m-kx in [0,26] guaranteed
              const int q = m - kx;
              acc[q] = (m & 1) ? pk_fma_bhi(wv[kx][ic], p[ic], acc[q])
                               : pk_fma_blo(wv[kx][ic], p[ic], acc[q]);
            }
          }
        }
      }
    }
    // half B: cols 16..31 in SGPRs (one batched wait)
    {
      f32x16 c0, c1, c2;
      asm volatile(
          "s_load_dwordx16 %0, %3, 0x40\n\t"
          "s_load_dwordx16 %1, %4, 0x40\n\t"
          "s_load_dwordx16 %2, %5, 0x40\n\t"
          "s_waitcnt lgkmcnt(0)"
          : "=&s"(c0), "=&s"(c1), "=&s"(c2)
          : "s"(r0), "s"(r1), "s"(r2));
      __builtin_amdgcn_sched_barrier(0);
#pragma unroll
      for (int m = 16; m < 32; ++m) {
        const int mm = m - 16;
        f32x2 p[3];
        p[0].x = c0[(mm >> 1) * 2]; p[0].y = c0[(mm >> 1) * 2 + 1];
        p[1].x = c1[(mm >> 1) * 2]; p[1].y = c1[(mm >> 1) * 2 + 1];
        p[2].x = c2[(mm >> 1) * 2]; p[2].y = c2[(mm >> 1) * 2 + 1];
#pragma unroll
        for (int ic = 0; ic < 3; ++ic) {        // ic OUTER: spreads dep chains
#pragma unroll
          for (int kx = 0; kx < 6; ++kx) {
            const int q = m - kx;
            if (q <= 26) {               // kx <= 5 <= m always
              acc[q] = (m & 1) ? pk_fma_bhi(wv[kx][ic], p[ic], acc[q])
                               : pk_fma_blo(wv[kx][ic], p[ic], acc[q]);
            }
          }
        }
      }
    }
  }
  float* dstbase = conv + ((size_t)(bl * 27 + y) * 27) * 2048;
#pragma unroll
  for (int q = 0; q < 27; ++q) {
    dstbase[(size_t)q * 2048 + cpair]        = acc[q].x;
    dstbase[(size_t)q * 2048 + cpair + 1024] = acc[q].y;
  }
}

// ------- kernel 3: 2-pixel register-resident rank-819 select + byte mask ----
// Round-7 version (best measured: 2.53 us/batch). UNCHANGED.
__global__ __launch_bounds__(256) void net99_select(const float* __restrict__ conv,
                                                    const float* __restrict__ bias,
                                                    uint8_t* __restrict__ mskb, int b0) {
  const int bl = blockIdx.x / 365;
  const int g  = blockIdx.x % 365;
  const int p0 = 2 * g;
  const bool has1 = (p0 + 1) < 729;
  const int gb = b0 + bl;
  const int tid  = threadIdx.x;
  const int lane = tid & 63;
  const int wid  = tid >> 6;
  const int nst  = has1 ? 4 : 2;
  __shared__ uint32_t hist[4][256];
  __shared__ float    cand[4][512];
  __shared__ int      cnt[4];
  __shared__ int      sbin[4], sbelow[4];
  __shared__ float    skth[4];

  const float4* __restrict__ s0 =
      (const float4*)(conv + ((size_t)bl * 729 + p0) * 2048) + tid * 2;
  const float4* __restrict__ b4 = (const float4*)bias + tid * 2;
  float4 va0 = s0[0], vb0 = s0[1];
  float4 va1 = {}, vb1 = {};
  if (has1) { va1 = s0[512]; vb1 = s0[513]; }
  float4 ba = b4[0], bb = b4[1];

  (&hist[0][0])[tid]       = 0u;
  (&hist[0][0])[tid + 256] = 0u;
  (&hist[0][0])[tid + 512] = 0u;
  (&hist[0][0])[tid + 768] = 0u;
  if (tid < 4) cnt[tid] = 0;

  float z[4][8];
  {
    float bv[8] = {ba.x, ba.y, ba.z, ba.w, bb.x, bb.y, bb.z, bb.w};
    float v0[8] = {va0.x, va0.y, va0.z, va0.w, vb0.x, vb0.y, vb0.z, vb0.w};
    float v1[8] = {va1.x, va1.y, va1.z, va1.w, vb1.x, vb1.y, vb1.z, vb1.w};
#pragma unroll
    for (int j = 0; j < 8; ++j) {
      z[0][j] = bv[j] - v0[j];   // single f32 op, matches reference
      z[1][j] = bv[j] + v0[j];
      z[2][j] = bv[j] - v1[j];
      z[3][j] = bv[j] + v1[j];
    }
  }
  __syncthreads();                                  // hist zeros visible
#pragma unroll
  for (int j = 0; j < 8; ++j) {
    atomicAdd(&hist[0][zbin256(z[0][j])], 1u);
    atomicAdd(&hist[1][zbin256(z[1][j])], 1u);
  }
  if (has1) {
#pragma unroll
    for (int j = 0; j < 8; ++j) {
      atomicAdd(&hist[2][zbin256(z[2][j])], 1u);
      atomicAdd(&hist[3][zbin256(z[3][j])], 1u);
    }
  }
  __syncthreads();
  if (wid < nst) {                      // wave w scans stream w (no barriers)
    const int s = wid;
    int h[4];
#pragma unroll
    for (int t = 0; t < 4; ++t) h[t] = (int)hist[s][lane * 4 + t];
    int loc = h[0] + h[1] + h[2] + h[3];
    int inc = loc;
#pragma unroll
    for (int off = 1; off < 64; off <<= 1) {
      int u = __shfl_up(inc, off);
      if (lane >= off) inc += u;
    }
    int pre = inc - loc;
    if (pre <= RANK_K && RANK_K < pre + loc) {      // exactly one lane
      int cum = pre;
#pragma unroll
      for (int t = 0; t < 4; ++t) {
        if (RANK_K < cum + h[t]) { sbin[s] = lane * 4 + t; sbelow[s] = cum; break; }
        cum += h[t];
      }
    }
  }
  __syncthreads();
#pragma unroll
  for (int s = 0; s < 4; ++s) {                     // compact from registers
    if (s >= 2 && !has1) break;
    const int tb = sbin[s];
#pragma unroll
    for (int j = 0; j < 8; ++j) {
      if (zbin256(z[s][j]) == tb) {
        int u = atomicAdd(&cnt[s], 1);
        if (u < 512) cand[s][u] = z[s][j];
      }
    }
  }
  __syncthreads();
  if (wid < nst) {                      // exact rank, one wave per stream
    const int s = wid;
    int cN = cnt[s] < 512 ? cnt[s] : 512;
    int rloc = RANK_K - sbelow[s];
    for (int ci = lane; ci < cN; ci += 64) {
      float v = cand[s][ci]; int rk = 0;
      for (int j = 0; j < cN; ++j) {
        float u = cand[s][j];
        rk += (u < v) || (u == v && j < ci);
      }
      if (rk == rloc) skth[s] = v;                  // unique winning VALUE
    }
  }
  __syncthreads();
  const size_t pix0 = (size_t)gb * 729 + p0;
  {
    uint32_t m0 = 0u, m1 = 0u;
    const float k0 = skth[0], k1 = skth[1];
#pragma unroll
    for (int j = 0; j < 8; ++j) {
      m0 |= (uint32_t)(z[0][j] < k0) << j;
      m1 |= (uint32_t)(z[1][j] < k1) << j;
    }
    mskb[pix0 * 256 + tid]                      = (uint8_t)m0;
    mskb[((size_t)64 * 729 + pix0) * 256 + tid] = (uint8_t)m1;
  }
  if (has1) {
    uint32_t m2 = 0u, m3 = 0u;
    const float k2 = skth[2], k3 = skth[3];
#pragma unroll
    for (int j = 0; j < 8; ++j) {
      m2 |= (uint32_t)(z[2][j] < k2) << j;
      m3 |= (uint32_t)(z[3][j] < k3) << j;
    }
    mskb[(pix0 + 1) * 256 + tid]                      = (uint8_t)m2;
    mskb[((size_t)64 * 729 + pix0 + 1) * 256 + tid]   = (uint8_t)m3;
  }
}

// ------- kernel 4: bit-exact avg_pool(5,3,ceil) + adaptive(6), LDS-staged ---
__global__ __launch_bounds__(256) void net99_pool(const uint32_t* __restrict__ msk,
                                                  float* __restrict__ out) {
  __shared__ uint32_t stage[729 * 8];   // 23,328 B: full (s,b,cg) mask slice
  const int blk = blockIdx.x;           // 0..1023 = (sb, cg)
  const int cg  = blk & 7;
  const int sb  = blk >> 3;             // s*64 + b
  const int tid = threadIdx.x;
  const uint32_t* src = msk + (size_t)sb * 729 * 64 + cg * 8;
  for (int i = tid; i < 729 * 8; i += 256) {
    int p = i >> 3, w = i & 7;
    stage[i] = src[(size_t)p * 64 + w];
  }
  __syncthreads();
  const int lw = tid >> 5, sel = tid & 31;
  uint32_t rbm[27];
  for (int y = 0; y < 27; ++y) {
    uint32_t rb = 0;
#pragma unroll
    for (int xx = 0; xx < 27; ++xx)
      rb |= ((stage[(y * 27 + xx) * 8 + lw] >> sel) & 1u) << xx;
    rbm[y] = rb;
  }
  constexpr uint32_t WM[9] = {0x1Fu, 0xF8u, 0x7C0u, 0x3E00u, 0x1F000u,
                              0xF8000u, 0x7C0000u, 0x3E00000u, 0x7000000u};
  constexpr int CC[9]  = {5, 5, 5, 5, 5, 5, 5, 5, 3};
  constexpr int BW0[6] = {0, 1, 3, 4, 6, 7};
  constexpr int BW1[6] = {1, 2, 4, 5, 7, 8};
  const int s = sb >> 6, b = sb & 63, c = cg * 256 + tid;
  float* dst = out + (size_t)s * 4718592 + (size_t)(b * 2048 + c) * 36;
  for (int i = 0; i < 6; ++i) {
    float P[2][9];
#pragma unroll
    for (int t = 0; t < 2; ++t) {
      int r  = t ? BW1[i] : BW0[i];
      int y0 = 3 * r;
      int y1 = (y0 + 5 > 27) ? 27 : y0 + 5;
      int cr = y1 - y0;
      int pp[9];
#pragma unroll
      for (int cx = 0; cx < 9; ++cx) pp[cx] = 0;
      for (int yy = y0; yy < y1; ++yy) {
        uint32_t rb = rbm[yy];
#pragma unroll
        for (int cx = 0; cx < 9; ++cx) pp[cx] += __popc(rb & WM[cx]);
      }
#pragma unroll
      for (int cx = 0; cx < 9; ++cx)
        P[t][cx] = (float)pp[cx] / (float)(cr * CC[cx]);   // IEEE f32 div
    }
    float M[9];
#pragma unroll
    for (int cx = 0; cx < 9; ++cx) M[cx] = (P[0][cx] + P[1][cx]) * 0.5f;
#pragma unroll
    for (int j = 0; j < 6; ++j)
      dst[i * 6 + j] = (M[BW0[j]] + M[BW1[j]]) * 0.5f;
  }
}

extern "C" void kernel_launch(void* const* d_in, const int* in_sizes, int n_in,
                              void* d_out, int out_size, void* d_ws, size_t ws_size,
                              hipStream_t stream) {
  const float* x    = (const float*)d_in[0];
  const float* w    = (const float*)d_in[1];
  const float* bias = (const float*)d_in[2];
  float* out = (float*)d_out;
  uint8_t* ws = (uint8_t*)d_ws;

  const size_t WT_BYTES   = (size_t)108 * 1024 * 8;          //   884,736
  const size_t MASK_OFF   = WT_BYTES;
  const size_t MASK_BYTES = (size_t)2 * 64 * 729 * 64 * 4;   // 23,887,872
  const size_t CONV_OFF   = MASK_OFF + MASK_BYTES;           // 24,772,608
  const size_t PER_B      = (size_t)2048 * 729 * 4;          // 5,971,968 per batch

  f32x2*    wt4  = (f32x2*)ws;
  uint8_t*  mskb = (uint8_t*)(ws + MASK_OFF);
  uint32_t* msk  = (uint32_t*)(ws + MASK_OFF);
  float*    conv = (float*)(ws + CONV_OFF);

  size_t avail = ws_size > CONV_OFF ? ws_size - CONV_OFF : 0;
  int Bc = (int)(avail / PER_B);
  if (Bc < 1) Bc = 1;       // assumes ws_size >= ~31 MB
  if (Bc > 64) Bc = 64;

  hipLaunchKernelGGL(net99_wtrans, dim3((108 * 1024 + 255) / 256), dim3(256), 0, stream, w, wt4);
  for (int b0 = 0; b0 < 64; b0 += Bc) {
    int nb = (64 - b0 < Bc) ? (64 - b0) : Bc;
    hipLaunchKernelGGL(net99_conv, dim3(27, 4, nb), dim3(256), 0, stream, x, wt4, conv, b0);
    hipLaunchKernelGGL(net99_select, dim3(nb * 365), dim3(256), 0, stream, conv, bias, mskb, b0);
  }
  hipLaunchKernelGGL(net99_pool, dim3(1024), dim3(256), 0, stream, msk, out);
}